// Round 16
// baseline (383.641 us; speedup 1.0000x reference)
//
#include <hip/hip_runtime.h>
#include <stdint.h>

#define NB 8
#define NT 32
#define NN 1024
#define KSEL 16

typedef unsigned long long u64;
typedef unsigned int u32;

// total output element offsets (all float32)
#define O_IDX0 0ull
#define O_DIST 4194304ull
#define O_IDX1 8388608ull
#define O_PTS  12582912ull
#define O_PF   25165824ull
#define O_NORM 50331648ull
#define O_OUTX 62914560ull

#define F32_INF __uint_as_float(0x7F800000u)

#if __has_builtin(__builtin_amdgcn_fmed3f)
#define MED3(X, A, B) __builtin_amdgcn_fmed3f((X), (A), (B))
#else
#define MED3(X, A, B) __builtin_fminf(__builtin_fmaxf((X), (A)), (B))
#endif

__device__ __forceinline__ u32 fmap(float f) {
    u32 b = __float_as_uint(f);
    u32 m = (u32)((int)b >> 31) | 0x80000000u;
    return b ^ m;
}
// XLA-CPU reduce(sum(x*x)) with LLVM FMA contraction: fma(z,z, fma(x,x, y*y))
__device__ __forceinline__ float sq3(float x, float y, float z) {
    return __fmaf_rn(z, z, __fmaf_rn(x, x, __fmul_rn(y, y)));
}
// Eigen sgemm ascending-k FMA dot; d2 = (q2+p2) - 2*dot (2*dot exact)
__device__ __forceinline__ float d2f(float qx, float qy, float qz, float q2, float4 c) {
    float dot = __fmul_rn(qx, c.x);
    dot = __fmaf_rn(qy, c.y, dot);
    dot = __fmaf_rn(qz, c.z, dot);
    return __fsub_rn(__fadd_rn(q2, c.w), __fadd_rn(dot, dot));
}

// r9/r10-HW-verified exact stable insert; med3 K-update (r13/r14/r15-verified).
#define INSERT16(D2V, JV)                                                        \
{                                                                                \
    _Pragma("unroll")                                                            \
    for (int s = KSEL - 1; s >= 1; --s) {                                        \
        ID[s] = ((D2V) < K[s - 1]) ? ID[s - 1] : (((D2V) < K[s]) ? (JV) : ID[s]);\
        K[s]  = MED3((D2V), K[s - 1], K[s]);                                     \
    }                                                                            \
    ID[0] = ((D2V) < K[0]) ? (JV) : ID[0];                                       \
    K[0]  = __builtin_fminf((D2V), K[0]);                                        \
}

// ---------------- Phase 1: nearest-neighbor chain (k=1), writes outx ----------------
// r10/r11/r12/r15-HW-verified fast version. grid: 1024 blocks, 256 = 8 q x 32 lanes
__global__ __launch_bounds__(256) void chain_k(const float* __restrict__ P,
                                               float* __restrict__ outx) {
    __shared__ float4 sF[NN];
    const int tid = threadIdx.x;
    const int bid = blockIdx.x;
    const int b = bid >> 7;
    const int qb = (bid & 127) << 3;
    const int ln = tid & 63;
    const int q = qb + ((tid >> 6) << 1) + (ln >> 5);
    const int sl = ln & 31;
    const float* bp = P + (size_t)b * NT * NN * 3;

    float cx = bp[q * 3 + 0], cy = bp[q * 3 + 1], cz = bp[q * 3 + 2];

    for (int t = 0; t < NT; ++t) {
        // stage frame t with |p|^2 (thread i -> candidates 4i..4i+3)
        const float4* f4 = (const float4*)(bp + (size_t)t * NN * 3);
        float4 A = f4[tid * 3 + 0], Bv = f4[tid * 3 + 1], C = f4[tid * 3 + 2];
        sF[tid * 4 + 0] = make_float4(A.x, A.y, A.z, sq3(A.x, A.y, A.z));
        sF[tid * 4 + 1] = make_float4(A.w, Bv.x, Bv.y, sq3(A.w, Bv.x, Bv.y));
        sF[tid * 4 + 2] = make_float4(Bv.z, Bv.w, C.x, sq3(Bv.z, Bv.w, C.x));
        sF[tid * 4 + 3] = make_float4(C.y, C.z, C.w, sq3(C.y, C.z, C.w));
        __syncthreads();

        float q2 = sq3(cx, cy, cz);
        float bd = F32_INF;
        u32 bj = 0u;
        #pragma unroll 8
        for (int i = 0; i < 32; ++i) {
            int j = (i << 5) | sl;          // ascending per lane -> stable in-lane
            float d2 = d2f(cx, cy, cz, q2, sF[j]);
            bool c_ = d2 < bd;
            bd = c_ ? d2 : bd;
            bj = c_ ? (u32)j : bj;
        }
        // cross-lane exact argmin with lowest-index tie-break via packed key
        u64 key = ((u64)fmap(bd) << 32) | (u64)bj;
        #pragma unroll
        for (int off = 1; off < 32; off <<= 1) {
            u64 o = __shfl_xor(key, off);
            key = (o < key) ? o : key;
        }
        int bi = (int)((u32)key & 1023u);
        float4 w = sF[bi];
        cx = w.x; cy = w.y; cz = w.z;
        if (sl == 0) {
            float* o = outx + ((size_t)(b * NT + t) * NN + q) * 3;
            o[0] = cx; o[1] = cy; o[2] = cz;
        }
        __syncthreads();
    }
}

// ---------------- Phase 2: exact LDS filter + bitmask replay top-16 (r9 core) -------
// grid: 2048 blocks (b:8 x t:32 x qc:8), block: 128 threads = 128 queries.
// Selection algebra byte-identical to r15 (r9-verified). Deltas: sPv dropped
// (feats read from global prev-frame in epilogue; L2-resident, bitwise-identical
// values), LDS 16KB -> 8 blocks/CU, finer drain granularity.
__global__ __launch_bounds__(128, 4) void topk_k(const float* __restrict__ P,
                                                 const float* __restrict__ outx,
                                                 float* __restrict__ out) {
    __shared__ float4 sC[NN];  // frame t (x,y,z,|p|^2) 16KB
    const int tid = threadIdx.x;
    const int bid = blockIdx.x;
    const int b = bid >> 8;
    const int t = (bid >> 3) & 31;
    const int qc = bid & 7;
    const int q = (qc << 7) | tid;
    const float* bp = P + (size_t)b * NT * NN * 3;
    const int tp = (t == 0) ? 0 : (t - 1);
    const float* fpv = bp + (size_t)tp * NN * 3;  // prev frame (feats source)

    {
        // thread i unpacks 6 raw float4 (= 8 points) -> sC[8i..8i+7]
        const float4* f4 = (const float4*)(bp + (size_t)t * NN * 3);
        float4 A = f4[tid * 6 + 0], B = f4[tid * 6 + 1], C = f4[tid * 6 + 2];
        sC[tid * 8 + 0] = make_float4(A.x, A.y, A.z, sq3(A.x, A.y, A.z));
        sC[tid * 8 + 1] = make_float4(A.w, B.x, B.y, sq3(A.w, B.x, B.y));
        sC[tid * 8 + 2] = make_float4(B.z, B.w, C.x, sq3(B.z, B.w, C.x));
        sC[tid * 8 + 3] = make_float4(C.y, C.z, C.w, sq3(C.y, C.z, C.w));
        float4 D = f4[tid * 6 + 3], E = f4[tid * 6 + 4], F = f4[tid * 6 + 5];
        sC[tid * 8 + 4] = make_float4(D.x, D.y, D.z, sq3(D.x, D.y, D.z));
        sC[tid * 8 + 5] = make_float4(D.w, E.x, E.y, sq3(D.w, E.x, E.y));
        sC[tid * 8 + 6] = make_float4(E.z, E.w, F.x, sq3(E.z, E.w, F.x));
        sC[tid * 8 + 7] = make_float4(F.y, F.z, F.w, sq3(F.y, F.z, F.w));
    }
    __syncthreads();

    // query point: x_cur(b,t,q)
    float cx, cy, cz;
    if (t == 0) {
        const float* qp = bp + (size_t)q * 3;
        cx = qp[0]; cy = qp[1]; cz = qp[2];
    } else {
        const float* qp = outx + ((size_t)(b * NT + (t - 1)) * NN + q) * 3;
        cx = qp[0]; cy = qp[1]; cz = qp[2];
    }
    // anchor = pts[b, t=0, q, k=0] = outx[b][0][q]
    const float* ap = outx + ((size_t)(b * NT) * NN + q) * 3;
    float ax = ap[0], ay = ap[1], az = ap[2];

    float q2 = sq3(cx, cy, cz);
    float K[KSEL];
    u32 ID[KSEL];
    #pragma unroll
    for (int i = 0; i < KSEL; i++) { K[i] = F32_INF; ID[i] = 0u; }

    // ---- chunk 0: direct exact fill (thr would be INF anyway) [verified] ----
    for (u32 j = 0; j < 64; ++j) {
        float d2 = d2f(cx, cy, cz, q2, sC[j]);
        INSERT16(d2, j)
    }
    float thr = K[KSEL - 1];

    // ---- chunks 1..15: exact LDS filter + bitmask exact replay [r9-verified] ----
    for (int ch = 1; ch < 16; ++ch) {
        u32 mlo = 0u, mhi = 0u;
        #pragma unroll
        for (int jj = 0; jj < 64; ++jj) {
            float d2 = d2f(cx, cy, cz, q2, sC[(ch << 6) | jj]);
            bool h = d2 < thr;
            if (jj < 32) mlo |= h ? (1u << jj) : 0u;
            else         mhi |= h ? (1u << (jj - 32)) : 0u;
        }
        u64 msk = ((u64)mhi << 32) | (u64)mlo;
        int cm = __builtin_popcountll(msk);
        #pragma unroll
        for (int off = 1; off < 64; off <<= 1) {
            int o = __shfl_xor(cm, off);
            cm = (o > cm) ? o : cm;
        }
        cm = __builtin_amdgcn_readfirstlane(cm);
        for (int i = 0; i < cm; ++i) {
            bool act = msk != 0ull;
            u64 mm = act ? msk : 1ull;
            u32 jj = (u32)__builtin_ctzll(mm);
            msk &= (msk - 1ull);
            u32 j = ((u32)ch << 6) | jj;
            float4 c = sC[j];
            float d2 = d2f(cx, cy, cz, q2, c);
            float d2v = act ? d2 : F32_INF;  // neutralize exhausted lanes
            INSERT16(d2v, j)
        }
        thr = K[KSEL - 1];
    }

    size_t g = (size_t)(b * NT + t) * NN + q;

    // idxs (x2) and dist
    #pragma unroll
    for (int kk = 0; kk < KSEL; kk += 4) {
        float4 fi = make_float4((float)ID[kk + 0], (float)ID[kk + 1],
                                (float)ID[kk + 2], (float)ID[kk + 3]);
        float4 fd = make_float4(K[kk + 0], K[kk + 1], K[kk + 2], K[kk + 3]);
        *(float4*)(out + O_IDX0 + g * 16 + kk) = fi;
        *(float4*)(out + O_IDX1 + g * 16 + kk) = fi;
        *(float4*)(out + O_DIST + g * 16 + kk) = fd;
    }

    // pts, normalized, patchlet_feats (feats from global prev frame, L2-resident)
    #pragma unroll
    for (int kk = 0; kk < KSEL; kk += 4) {
        u32 i0 = ID[kk + 0], i1 = ID[kk + 1], i2 = ID[kk + 2], i3 = ID[kk + 3];
        float4 p0 = sC[i0], p1 = sC[i1], p2v = sC[i2], p3 = sC[i3];
        float f0x = fpv[i0 * 3 + 0], f0y = fpv[i0 * 3 + 1], f0z = fpv[i0 * 3 + 2];
        float f1x = fpv[i1 * 3 + 0], f1y = fpv[i1 * 3 + 1], f1z = fpv[i1 * 3 + 2];
        float f2x = fpv[i2 * 3 + 0], f2y = fpv[i2 * 3 + 1], f2z = fpv[i2 * 3 + 2];
        float f3x = fpv[i3 * 3 + 0], f3y = fpv[i3 * 3 + 1], f3z = fpv[i3 * 3 + 2];
        float n0x = p0.x - ax, n0y = p0.y - ay, n0z = p0.z - az;
        float n1x = p1.x - ax, n1y = p1.y - ay, n1z = p1.z - az;
        float n2x = p2v.x - ax, n2y = p2v.y - ay, n2z = p2v.z - az;
        float n3x = p3.x - ax, n3y = p3.y - ay, n3z = p3.z - az;

        float* pp = out + O_PTS + g * 48 + kk * 3;
        ((float4*)pp)[0] = make_float4(p0.x, p0.y, p0.z, p1.x);
        ((float4*)pp)[1] = make_float4(p1.y, p1.z, p2v.x, p2v.y);
        ((float4*)pp)[2] = make_float4(p2v.z, p3.x, p3.y, p3.z);

        float* np = out + O_NORM + g * 48 + kk * 3;
        ((float4*)np)[0] = make_float4(n0x, n0y, n0z, n1x);
        ((float4*)np)[1] = make_float4(n1y, n1z, n2x, n2y);
        ((float4*)np)[2] = make_float4(n2z, n3x, n3y, n3z);

        float* fp = out + O_PF + g * 96 + kk * 6;
        ((float4*)fp)[0] = make_float4(f0x, f0y, f0z, n0x);
        ((float4*)fp)[1] = make_float4(n0y, n0z, f1x, f1y);
        ((float4*)fp)[2] = make_float4(f1z, n1x, n1y, n1z);
        ((float4*)fp)[3] = make_float4(f2x, f2y, f2z, n2x);
        ((float4*)fp)[4] = make_float4(n2y, n2z, f3x, f3y);
        ((float4*)fp)[5] = make_float4(f3z, n3x, n3y, n3z);
    }
}

extern "C" void kernel_launch(void* const* d_in, const int* in_sizes, int n_in,
                              void* d_out, int out_size, void* d_ws, size_t ws_size,
                              hipStream_t stream) {
    const float* P = (const float*)d_in[0];
    float* out = (float*)d_out;
    float* outx = out + O_OUTX;
    chain_k<<<dim3(1024), dim3(256), 0, stream>>>(P, outx);
    topk_k<<<dim3(2048), dim3(128), 0, stream>>>(P, outx, out);
}

// Round 17
// 374.594 us; speedup vs baseline: 1.0242x; 1.0242x over previous
//
#include <hip/hip_runtime.h>
#include <stdint.h>

#define NB 8
#define NT 32
#define NN 1024
#define KSEL 16

typedef unsigned long long u64;
typedef unsigned int u32;

// total output element offsets (all float32)
#define O_IDX0 0ull
#define O_DIST 4194304ull
#define O_IDX1 8388608ull
#define O_PTS  12582912ull
#define O_PF   25165824ull
#define O_NORM 50331648ull
#define O_OUTX 62914560ull

#define F32_INF __uint_as_float(0x7F800000u)
// |dot-form filter - exact d2f| < ~1e-4 worst case on this data; 1e-3 margin is
// safely conservative (r10 HW-verified this exact filter+replay: absmax 0)
#define MARGIN 1e-3f

#if __has_builtin(__builtin_amdgcn_fmed3f)
#define MED3(X, A, B) __builtin_amdgcn_fmed3f((X), (A), (B))
#else
#define MED3(X, A, B) __builtin_fminf(__builtin_fmaxf((X), (A)), (B))
#endif

__device__ __forceinline__ u32 fmap(float f) {
    u32 b = __float_as_uint(f);
    u32 m = (u32)((int)b >> 31) | 0x80000000u;
    return b ^ m;
}
// XLA-CPU reduce(sum(x*x)) with LLVM FMA contraction: fma(z,z, fma(x,x, y*y))
__device__ __forceinline__ float sq3(float x, float y, float z) {
    return __fmaf_rn(z, z, __fmaf_rn(x, x, __fmul_rn(y, y)));
}
// Eigen sgemm ascending-k FMA dot; d2 = (q2+p2) - 2*dot (2*dot exact)
__device__ __forceinline__ float d2f(float qx, float qy, float qz, float q2, float4 c) {
    float dot = __fmul_rn(qx, c.x);
    dot = __fmaf_rn(qy, c.y, dot);
    dot = __fmaf_rn(qz, c.z, dot);
    return __fsub_rn(__fadd_rn(q2, c.w), __fadd_rn(dot, dot));
}

// r9/r10-HW-verified exact stable insert; med3 K-update (r13/r14/r15-verified).
#define INSERT16(D2V, JV)                                                        \
{                                                                                \
    _Pragma("unroll")                                                            \
    for (int s = KSEL - 1; s >= 1; --s) {                                        \
        ID[s] = ((D2V) < K[s - 1]) ? ID[s - 1] : (((D2V) < K[s]) ? (JV) : ID[s]);\
        K[s]  = MED3((D2V), K[s - 1], K[s]);                                     \
    }                                                                            \
    ID[0] = ((D2V) < K[0]) ? (JV) : ID[0];                                       \
    K[0]  = __builtin_fminf((D2V), K[0]);                                        \
}

// ---------------- Phase 1: nearest-neighbor chain (k=1), writes outx ----------------
// r10/r11/r12/r15-HW-verified fast version. grid: 1024 blocks, 256 = 8 q x 32 lanes
__global__ __launch_bounds__(256) void chain_k(const float* __restrict__ P,
                                               float* __restrict__ outx) {
    __shared__ float4 sF[NN];
    const int tid = threadIdx.x;
    const int bid = blockIdx.x;
    const int b = bid >> 7;
    const int qb = (bid & 127) << 3;
    const int ln = tid & 63;
    const int q = qb + ((tid >> 6) << 1) + (ln >> 5);
    const int sl = ln & 31;
    const float* bp = P + (size_t)b * NT * NN * 3;

    float cx = bp[q * 3 + 0], cy = bp[q * 3 + 1], cz = bp[q * 3 + 2];

    for (int t = 0; t < NT; ++t) {
        // stage frame t with |p|^2 (thread i -> candidates 4i..4i+3)
        const float4* f4 = (const float4*)(bp + (size_t)t * NN * 3);
        float4 A = f4[tid * 3 + 0], Bv = f4[tid * 3 + 1], C = f4[tid * 3 + 2];
        sF[tid * 4 + 0] = make_float4(A.x, A.y, A.z, sq3(A.x, A.y, A.z));
        sF[tid * 4 + 1] = make_float4(A.w, Bv.x, Bv.y, sq3(A.w, Bv.x, Bv.y));
        sF[tid * 4 + 2] = make_float4(Bv.z, Bv.w, C.x, sq3(Bv.z, Bv.w, C.x));
        sF[tid * 4 + 3] = make_float4(C.y, C.z, C.w, sq3(C.y, C.z, C.w));
        __syncthreads();

        float q2 = sq3(cx, cy, cz);
        float bd = F32_INF;
        u32 bj = 0u;
        #pragma unroll 8
        for (int i = 0; i < 32; ++i) {
            int j = (i << 5) | sl;          // ascending per lane -> stable in-lane
            float d2 = d2f(cx, cy, cz, q2, sF[j]);
            bool c_ = d2 < bd;
            bd = c_ ? d2 : bd;
            bj = c_ ? (u32)j : bj;
        }
        // cross-lane exact argmin with lowest-index tie-break via packed key
        u64 key = ((u64)fmap(bd) << 32) | (u64)bj;
        #pragma unroll
        for (int off = 1; off < 32; off <<= 1) {
            u64 o = __shfl_xor(key, off);
            key = (o < key) ? o : key;
        }
        int bi = (int)((u32)key & 1023u);
        float4 w = sF[bi];
        cx = w.x; cy = w.y; cz = w.z;
        if (sl == 0) {
            float* o = outx + ((size_t)(b * NT + t) * NN + q) * 3;
            o[0] = cx; o[1] = cy; o[2] = cz;
        }
        __syncthreads();
    }
}

// ---------------- Phase 2: margin LDS filter + bitmask exact replay (r15 base) ------
// r15-HW-verified structure verbatim (best measured: topk ~300us). Single delta:
// filter uses r10's HW-verified 4-op dot-form with conservative margin; replay
// still computes exact d2f + exact strict-< inserts => bitwise-identical output.
__global__ __launch_bounds__(256, 4) void topk_k(const float* __restrict__ P,
                                                 const float* __restrict__ outx,
                                                 float* __restrict__ out) {
    __shared__ float4 sC[NN];  // frame t   (x,y,z,|p|^2) 16KB
    __shared__ float4 sPv[NN]; // frame t-1 (x,y,z,0)     16KB
    const int tid = threadIdx.x;
    const int bid = blockIdx.x;
    const int b = bid >> 7;
    const int t = (bid >> 2) & 31;
    const int qc = bid & 3;
    const int q = (qc << 8) | tid;
    const float* bp = P + (size_t)b * NT * NN * 3;

    {
        const float4* f4 = (const float4*)(bp + (size_t)t * NN * 3);
        float4 A = f4[tid * 3 + 0], Bv = f4[tid * 3 + 1], C = f4[tid * 3 + 2];
        sC[tid * 4 + 0] = make_float4(A.x, A.y, A.z, sq3(A.x, A.y, A.z));
        sC[tid * 4 + 1] = make_float4(A.w, Bv.x, Bv.y, sq3(A.w, Bv.x, Bv.y));
        sC[tid * 4 + 2] = make_float4(Bv.z, Bv.w, C.x, sq3(Bv.z, Bv.w, C.x));
        sC[tid * 4 + 3] = make_float4(C.y, C.z, C.w, sq3(C.y, C.z, C.w));
        int tp = (t == 0) ? 0 : (t - 1);
        const float4* g4 = (const float4*)(bp + (size_t)tp * NN * 3);
        A = g4[tid * 3 + 0]; Bv = g4[tid * 3 + 1]; C = g4[tid * 3 + 2];
        sPv[tid * 4 + 0] = make_float4(A.x, A.y, A.z, 0.f);
        sPv[tid * 4 + 1] = make_float4(A.w, Bv.x, Bv.y, 0.f);
        sPv[tid * 4 + 2] = make_float4(Bv.z, Bv.w, C.x, 0.f);
        sPv[tid * 4 + 3] = make_float4(C.y, C.z, C.w, 0.f);
    }
    __syncthreads();

    // query point: x_cur(b,t,q)
    float cx, cy, cz;
    if (t == 0) {
        const float* qp = bp + (size_t)q * 3;
        cx = qp[0]; cy = qp[1]; cz = qp[2];
    } else {
        const float* qp = outx + ((size_t)(b * NT + (t - 1)) * NN + q) * 3;
        cx = qp[0]; cy = qp[1]; cz = qp[2];
    }
    // anchor = pts[b, t=0, q, k=0] = outx[b][0][q]
    const float* ap = outx + ((size_t)(b * NT) * NN + q) * 3;
    float ax = ap[0], ay = ap[1], az = ap[2];

    float q2 = sq3(cx, cy, cz);
    float K[KSEL];
    u32 ID[KSEL];
    #pragma unroll
    for (int i = 0; i < KSEL; i++) { K[i] = F32_INF; ID[i] = 0u; }

    // ---- chunk 0: direct exact fill (thr would be INF anyway) [verified] ----
    for (u32 j = 0; j < 64; ++j) {
        float d2 = d2f(cx, cy, cz, q2, sC[j]);
        INSERT16(d2, j)
    }
    float thr = K[KSEL - 1];

    // ---- chunks 1..15: 4-op margin filter [r10-verified] + exact replay [r9] ----
    for (int ch = 1; ch < 16; ++ch) {
        float thrq = __fadd_rn(__fsub_rn(thr, q2), MARGIN);
        u32 mlo = 0u, mhi = 0u;
        #pragma unroll
        for (int jj = 0; jj < 64; ++jj) {
            float4 c = sC[(ch << 6) | jj];
            float dt = __fmaf_rn(c.z, cz, __fmaf_rn(c.y, cy, __fmul_rn(c.x, cx)));
            float lhs = __fmaf_rn(-2.0f, dt, c.w);
            bool h = lhs < thrq;
            if (jj < 32) mlo |= h ? (1u << jj) : 0u;
            else         mhi |= h ? (1u << (jj - 32)) : 0u;
        }
        u64 msk = ((u64)mhi << 32) | (u64)mlo;
        int cm = __builtin_popcountll(msk);
        #pragma unroll
        for (int off = 1; off < 64; off <<= 1) {
            int o = __shfl_xor(cm, off);
            cm = (o > cm) ? o : cm;
        }
        cm = __builtin_amdgcn_readfirstlane(cm);
        for (int i = 0; i < cm; ++i) {
            bool act = msk != 0ull;
            u64 mm = act ? msk : 1ull;
            u32 jj = (u32)__builtin_ctzll(mm);
            msk &= (msk - 1ull);
            u32 j = ((u32)ch << 6) | jj;
            float4 c = sC[j];
            float d2 = d2f(cx, cy, cz, q2, c);
            float d2v = act ? d2 : F32_INF;  // neutralize exhausted lanes
            INSERT16(d2v, j)
        }
        thr = K[KSEL - 1];
    }

    size_t g = (size_t)(b * NT + t) * NN + q;

    // idxs (x2) and dist
    #pragma unroll
    for (int kk = 0; kk < KSEL; kk += 4) {
        float4 fi = make_float4((float)ID[kk + 0], (float)ID[kk + 1],
                                (float)ID[kk + 2], (float)ID[kk + 3]);
        float4 fd = make_float4(K[kk + 0], K[kk + 1], K[kk + 2], K[kk + 3]);
        *(float4*)(out + O_IDX0 + g * 16 + kk) = fi;
        *(float4*)(out + O_IDX1 + g * 16 + kk) = fi;
        *(float4*)(out + O_DIST + g * 16 + kk) = fd;
    }

    // pts, normalized, patchlet_feats
    #pragma unroll
    for (int kk = 0; kk < KSEL; kk += 4) {
        u32 i0 = ID[kk + 0], i1 = ID[kk + 1], i2 = ID[kk + 2], i3 = ID[kk + 3];
        float4 p0 = sC[i0], p1 = sC[i1], p2v = sC[i2], p3 = sC[i3];
        float4 f0 = sPv[i0], f1 = sPv[i1], f2v = sPv[i2], f3 = sPv[i3];
        float n0x = p0.x - ax, n0y = p0.y - ay, n0z = p0.z - az;
        float n1x = p1.x - ax, n1y = p1.y - ay, n1z = p1.z - az;
        float n2x = p2v.x - ax, n2y = p2v.y - ay, n2z = p2v.z - az;
        float n3x = p3.x - ax, n3y = p3.y - ay, n3z = p3.z - az;

        float* pp = out + O_PTS + g * 48 + kk * 3;
        ((float4*)pp)[0] = make_float4(p0.x, p0.y, p0.z, p1.x);
        ((float4*)pp)[1] = make_float4(p1.y, p1.z, p2v.x, p2v.y);
        ((float4*)pp)[2] = make_float4(p2v.z, p3.x, p3.y, p3.z);

        float* np = out + O_NORM + g * 48 + kk * 3;
        ((float4*)np)[0] = make_float4(n0x, n0y, n0z, n1x);
        ((float4*)np)[1] = make_float4(n1y, n1z, n2x, n2y);
        ((float4*)np)[2] = make_float4(n2z, n3x, n3y, n3z);

        float* fp = out + O_PF + g * 96 + kk * 6;
        ((float4*)fp)[0] = make_float4(f0.x, f0.y, f0.z, n0x);
        ((float4*)fp)[1] = make_float4(n0y, n0z, f1.x, f1.y);
        ((float4*)fp)[2] = make_float4(f1.z, n1x, n1y, n1z);
        ((float4*)fp)[3] = make_float4(f2v.x, f2v.y, f2v.z, n2x);
        ((float4*)fp)[4] = make_float4(n2y, n2z, f3.x, f3.y);
        ((float4*)fp)[5] = make_float4(f3.z, n3x, n3y, n3z);
    }
}

extern "C" void kernel_launch(void* const* d_in, const int* in_sizes, int n_in,
                              void* d_out, int out_size, void* d_ws, size_t ws_size,
                              hipStream_t stream) {
    const float* P = (const float*)d_in[0];
    float* out = (float*)d_out;
    float* outx = out + O_OUTX;
    chain_k<<<dim3(1024), dim3(256), 0, stream>>>(P, outx);
    topk_k<<<dim3(1024), dim3(256), 0, stream>>>(P, outx, out);
}

// Round 18
// 370.762 us; speedup vs baseline: 1.0347x; 1.0103x over previous
//
#include <hip/hip_runtime.h>
#include <stdint.h>

#define NB 8
#define NT 32
#define NN 1024
#define KSEL 16

typedef unsigned long long u64;
typedef unsigned int u32;

// total output element offsets (all float32)
#define O_IDX0 0ull
#define O_DIST 4194304ull
#define O_IDX1 8388608ull
#define O_PTS  12582912ull
#define O_PF   25165824ull
#define O_NORM 50331648ull
#define O_OUTX 62914560ull

#define F32_INF __uint_as_float(0x7F800000u)

#if __has_builtin(__builtin_amdgcn_fmed3f)
#define MED3(X, A, B) __builtin_amdgcn_fmed3f((X), (A), (B))
#else
#define MED3(X, A, B) __builtin_fminf(__builtin_fmaxf((X), (A)), (B))
#endif

__device__ __forceinline__ u32 fmap(float f) {
    u32 b = __float_as_uint(f);
    u32 m = (u32)((int)b >> 31) | 0x80000000u;
    return b ^ m;
}
// XLA-CPU reduce(sum(x*x)) with LLVM FMA contraction: fma(z,z, fma(x,x, y*y))
__device__ __forceinline__ float sq3(float x, float y, float z) {
    return __fmaf_rn(z, z, __fmaf_rn(x, x, __fmul_rn(y, y)));
}
// Eigen sgemm ascending-k FMA dot; d2 = (q2+p2) - 2*dot (2*dot exact)
__device__ __forceinline__ float d2f(float qx, float qy, float qz, float q2, float4 c) {
    float dot = __fmul_rn(qx, c.x);
    dot = __fmaf_rn(qy, c.y, dot);
    dot = __fmaf_rn(qz, c.z, dot);
    return __fsub_rn(__fadd_rn(q2, c.w), __fadd_rn(dot, dot));
}

// r9/r10-HW-verified exact stable insert; med3 K-update (r13/r14/r15-verified).
#define INSERT16(D2V, JV)                                                        \
{                                                                                \
    _Pragma("unroll")                                                            \
    for (int s = KSEL - 1; s >= 1; --s) {                                        \
        ID[s] = ((D2V) < K[s - 1]) ? ID[s - 1] : (((D2V) < K[s]) ? (JV) : ID[s]);\
        K[s]  = MED3((D2V), K[s - 1], K[s]);                                     \
    }                                                                            \
    ID[0] = ((D2V) < K[0]) ? (JV) : ID[0];                                       \
    K[0]  = __builtin_fminf((D2V), K[0]);                                        \
}

// ---------------- Phase 1: nearest-neighbor chain (k=1), writes outx ----------------
// r10/r11/r12/r15-HW-verified fast version. grid: 1024 blocks, 256 = 8 q x 32 lanes
__global__ __launch_bounds__(256) void chain_k(const float* __restrict__ P,
                                               float* __restrict__ outx) {
    __shared__ float4 sF[NN];
    const int tid = threadIdx.x;
    const int bid = blockIdx.x;
    const int b = bid >> 7;
    const int qb = (bid & 127) << 3;
    const int ln = tid & 63;
    const int q = qb + ((tid >> 6) << 1) + (ln >> 5);
    const int sl = ln & 31;
    const float* bp = P + (size_t)b * NT * NN * 3;

    float cx = bp[q * 3 + 0], cy = bp[q * 3 + 1], cz = bp[q * 3 + 2];

    for (int t = 0; t < NT; ++t) {
        // stage frame t with |p|^2 (thread i -> candidates 4i..4i+3)
        const float4* f4 = (const float4*)(bp + (size_t)t * NN * 3);
        float4 A = f4[tid * 3 + 0], Bv = f4[tid * 3 + 1], C = f4[tid * 3 + 2];
        sF[tid * 4 + 0] = make_float4(A.x, A.y, A.z, sq3(A.x, A.y, A.z));
        sF[tid * 4 + 1] = make_float4(A.w, Bv.x, Bv.y, sq3(A.w, Bv.x, Bv.y));
        sF[tid * 4 + 2] = make_float4(Bv.z, Bv.w, C.x, sq3(Bv.z, Bv.w, C.x));
        sF[tid * 4 + 3] = make_float4(C.y, C.z, C.w, sq3(C.y, C.z, C.w));
        __syncthreads();

        float q2 = sq3(cx, cy, cz);
        float bd = F32_INF;
        u32 bj = 0u;
        #pragma unroll 8
        for (int i = 0; i < 32; ++i) {
            int j = (i << 5) | sl;          // ascending per lane -> stable in-lane
            float d2 = d2f(cx, cy, cz, q2, sF[j]);
            bool c_ = d2 < bd;
            bd = c_ ? d2 : bd;
            bj = c_ ? (u32)j : bj;
        }
        // cross-lane exact argmin with lowest-index tie-break via packed key
        u64 key = ((u64)fmap(bd) << 32) | (u64)bj;
        #pragma unroll
        for (int off = 1; off < 32; off <<= 1) {
            u64 o = __shfl_xor(key, off);
            key = (o < key) ? o : key;
        }
        int bi = (int)((u32)key & 1023u);
        float4 w = sF[bi];
        cx = w.x; cy = w.y; cz = w.z;
        if (sl == 0) {
            float* o = outx + ((size_t)(b * NT + t) * NN + q) * 3;
            o[0] = cx; o[1] = cy; o[2] = cz;
        }
        __syncthreads();
    }
}

// ---------------- Phase 2: exact LDS filter + PIPELINED bitmask replay --------------
// r15-HW-verified structure; single delta: the two serial insert loops are
// software-pipelined (next candidate's ds_read issued before current INSERT16)
// so insert ALU hides LDS latency. Identical candidate order and algebra =>
// bitwise-identical output.
__global__ __launch_bounds__(256, 4) void topk_k(const float* __restrict__ P,
                                                 const float* __restrict__ outx,
                                                 float* __restrict__ out) {
    __shared__ float4 sC[NN];  // frame t   (x,y,z,|p|^2) 16KB
    __shared__ float4 sPv[NN]; // frame t-1 (x,y,z,0)     16KB
    const int tid = threadIdx.x;
    const int bid = blockIdx.x;
    const int b = bid >> 7;
    const int t = (bid >> 2) & 31;
    const int qc = bid & 3;
    const int q = (qc << 8) | tid;
    const float* bp = P + (size_t)b * NT * NN * 3;

    {
        const float4* f4 = (const float4*)(bp + (size_t)t * NN * 3);
        float4 A = f4[tid * 3 + 0], Bv = f4[tid * 3 + 1], C = f4[tid * 3 + 2];
        sC[tid * 4 + 0] = make_float4(A.x, A.y, A.z, sq3(A.x, A.y, A.z));
        sC[tid * 4 + 1] = make_float4(A.w, Bv.x, Bv.y, sq3(A.w, Bv.x, Bv.y));
        sC[tid * 4 + 2] = make_float4(Bv.z, Bv.w, C.x, sq3(Bv.z, Bv.w, C.x));
        sC[tid * 4 + 3] = make_float4(C.y, C.z, C.w, sq3(C.y, C.z, C.w));
        int tp = (t == 0) ? 0 : (t - 1);
        const float4* g4 = (const float4*)(bp + (size_t)tp * NN * 3);
        A = g4[tid * 3 + 0]; Bv = g4[tid * 3 + 1]; C = g4[tid * 3 + 2];
        sPv[tid * 4 + 0] = make_float4(A.x, A.y, A.z, 0.f);
        sPv[tid * 4 + 1] = make_float4(A.w, Bv.x, Bv.y, 0.f);
        sPv[tid * 4 + 2] = make_float4(Bv.z, Bv.w, C.x, 0.f);
        sPv[tid * 4 + 3] = make_float4(C.y, C.z, C.w, 0.f);
    }
    __syncthreads();

    // query point: x_cur(b,t,q)
    float cx, cy, cz;
    if (t == 0) {
        const float* qp = bp + (size_t)q * 3;
        cx = qp[0]; cy = qp[1]; cz = qp[2];
    } else {
        const float* qp = outx + ((size_t)(b * NT + (t - 1)) * NN + q) * 3;
        cx = qp[0]; cy = qp[1]; cz = qp[2];
    }
    // anchor = pts[b, t=0, q, k=0] = outx[b][0][q]
    const float* ap = outx + ((size_t)(b * NT) * NN + q) * 3;
    float ax = ap[0], ay = ap[1], az = ap[2];

    float q2 = sq3(cx, cy, cz);
    float K[KSEL];
    u32 ID[KSEL];
    #pragma unroll
    for (int i = 0; i < KSEL; i++) { K[i] = F32_INF; ID[i] = 0u; }

    // ---- chunk 0: direct exact fill, pipelined 1-ahead ----
    {
        float4 c_cur = sC[0];
        #pragma unroll 4
        for (int j = 0; j < 64; ++j) {
            float4 c_nxt = sC[(j < 63) ? (j + 1) : 63];  // prefetch before insert
            float d2 = d2f(cx, cy, cz, q2, c_cur);
            INSERT16(d2, (u32)j)
            c_cur = c_nxt;
        }
    }
    float thr = K[KSEL - 1];

    // ---- chunks 1..15: exact LDS filter + pipelined bitmask exact replay ----
    for (int ch = 1; ch < 16; ++ch) {
        u32 mlo = 0u, mhi = 0u;
        #pragma unroll
        for (int jj = 0; jj < 64; ++jj) {
            float d2 = d2f(cx, cy, cz, q2, sC[(ch << 6) | jj]);
            bool h = d2 < thr;
            if (jj < 32) mlo |= h ? (1u << jj) : 0u;
            else         mhi |= h ? (1u << (jj - 32)) : 0u;
        }
        u64 msk = ((u64)mhi << 32) | (u64)mlo;
        int cm = __builtin_popcountll(msk);
        #pragma unroll
        for (int off = 1; off < 64; off <<= 1) {
            int o = __shfl_xor(cm, off);
            cm = (o > cm) ? o : cm;
        }
        cm = __builtin_amdgcn_readfirstlane(cm);

        // peel: extract first survivor + issue its load
        bool act_c = msk != 0ull;
        u64 mm0 = act_c ? msk : 1ull;
        u32 j_cur = ((u32)ch << 6) | (u32)__builtin_ctzll(mm0);
        msk &= (msk - 1ull);
        float4 c_cur = sC[j_cur];

        for (int i = 0; i < cm; ++i) {
            // extract NEXT survivor and issue its load before the current insert
            bool act_n = msk != 0ull;
            u64 mmn = act_n ? msk : 1ull;
            u32 j_nxt = ((u32)ch << 6) | (u32)__builtin_ctzll(mmn);
            msk &= (msk - 1ull);
            float4 c_nxt = sC[j_nxt];

            float d2 = d2f(cx, cy, cz, q2, c_cur);
            float d2v = act_c ? d2 : F32_INF;  // neutralize exhausted lanes
            INSERT16(d2v, j_cur)

            j_cur = j_nxt; c_cur = c_nxt; act_c = act_n;
        }
        thr = K[KSEL - 1];
    }

    size_t g = (size_t)(b * NT + t) * NN + q;

    // idxs (x2) and dist
    #pragma unroll
    for (int kk = 0; kk < KSEL; kk += 4) {
        float4 fi = make_float4((float)ID[kk + 0], (float)ID[kk + 1],
                                (float)ID[kk + 2], (float)ID[kk + 3]);
        float4 fd = make_float4(K[kk + 0], K[kk + 1], K[kk + 2], K[kk + 3]);
        *(float4*)(out + O_IDX0 + g * 16 + kk) = fi;
        *(float4*)(out + O_IDX1 + g * 16 + kk) = fi;
        *(float4*)(out + O_DIST + g * 16 + kk) = fd;
    }

    // pts, normalized, patchlet_feats
    #pragma unroll
    for (int kk = 0; kk < KSEL; kk += 4) {
        u32 i0 = ID[kk + 0], i1 = ID[kk + 1], i2 = ID[kk + 2], i3 = ID[kk + 3];
        float4 p0 = sC[i0], p1 = sC[i1], p2v = sC[i2], p3 = sC[i3];
        float4 f0 = sPv[i0], f1 = sPv[i1], f2v = sPv[i2], f3 = sPv[i3];
        float n0x = p0.x - ax, n0y = p0.y - ay, n0z = p0.z - az;
        float n1x = p1.x - ax, n1y = p1.y - ay, n1z = p1.z - az;
        float n2x = p2v.x - ax, n2y = p2v.y - ay, n2z = p2v.z - az;
        float n3x = p3.x - ax, n3y = p3.y - ay, n3z = p3.z - az;

        float* pp = out + O_PTS + g * 48 + kk * 3;
        ((float4*)pp)[0] = make_float4(p0.x, p0.y, p0.z, p1.x);
        ((float4*)pp)[1] = make_float4(p1.y, p1.z, p2v.x, p2v.y);
        ((float4*)pp)[2] = make_float4(p2v.z, p3.x, p3.y, p3.z);

        float* np = out + O_NORM + g * 48 + kk * 3;
        ((float4*)np)[0] = make_float4(n0x, n0y, n0z, n1x);
        ((float4*)np)[1] = make_float4(n1y, n1z, n2x, n2y);
        ((float4*)np)[2] = make_float4(n2z, n3x, n3y, n3z);

        float* fp = out + O_PF + g * 96 + kk * 6;
        ((float4*)fp)[0] = make_float4(f0.x, f0.y, f0.z, n0x);
        ((float4*)fp)[1] = make_float4(n0y, n0z, f1.x, f1.y);
        ((float4*)fp)[2] = make_float4(f1.z, n1x, n1y, n1z);
        ((float4*)fp)[3] = make_float4(f2v.x, f2v.y, f2v.z, n2x);
        ((float4*)fp)[4] = make_float4(n2y, n2z, f3.x, f3.y);
        ((float4*)fp)[5] = make_float4(f3.z, n3x, n3y, n3z);
    }
}

extern "C" void kernel_launch(void* const* d_in, const int* in_sizes, int n_in,
                              void* d_out, int out_size, void* d_ws, size_t ws_size,
                              hipStream_t stream) {
    const float* P = (const float*)d_in[0];
    float* out = (float*)d_out;
    float* outx = out + O_OUTX;
    chain_k<<<dim3(1024), dim3(256), 0, stream>>>(P, outx);
    topk_k<<<dim3(1024), dim3(256), 0, stream>>>(P, outx, out);
}

// Round 19
// 364.643 us; speedup vs baseline: 1.0521x; 1.0168x over previous
//
#include <hip/hip_runtime.h>
#include <stdint.h>

#define NB 8
#define NT 32
#define NN 1024
#define KSEL 16

typedef unsigned long long u64;
typedef unsigned int u32;

// total output element offsets (all float32)
#define O_IDX0 0ull
#define O_DIST 4194304ull
#define O_IDX1 8388608ull
#define O_PTS  12582912ull
#define O_PF   25165824ull
#define O_NORM 50331648ull
#define O_OUTX 62914560ull

#define F32_INF __uint_as_float(0x7F800000u)

#if __has_builtin(__builtin_amdgcn_fmed3f)
#define MED3(X, A, B) __builtin_amdgcn_fmed3f((X), (A), (B))
#else
#define MED3(X, A, B) __builtin_fminf(__builtin_fmaxf((X), (A)), (B))
#endif

__device__ __forceinline__ u32 fmap(float f) {
    u32 b = __float_as_uint(f);
    u32 m = (u32)((int)b >> 31) | 0x80000000u;
    return b ^ m;
}
// XLA-CPU reduce(sum(x*x)) with LLVM FMA contraction: fma(z,z, fma(x,x, y*y))
__device__ __forceinline__ float sq3(float x, float y, float z) {
    return __fmaf_rn(z, z, __fmaf_rn(x, x, __fmul_rn(y, y)));
}
// Eigen sgemm ascending-k FMA dot; d2 = (q2+p2) - 2*dot (2*dot exact)
__device__ __forceinline__ float d2f(float qx, float qy, float qz, float q2, float4 c) {
    float dot = __fmul_rn(qx, c.x);
    dot = __fmaf_rn(qy, c.y, dot);
    dot = __fmaf_rn(qz, c.z, dot);
    return __fsub_rn(__fadd_rn(q2, c.w), __fadd_rn(dot, dot));
}

// r9/r10-HW-verified exact stable insert; med3 K-update (r13/r14/r15-verified).
#define INSERT16(D2V, JV)                                                        \
{                                                                                \
    _Pragma("unroll")                                                            \
    for (int s = KSEL - 1; s >= 1; --s) {                                        \
        ID[s] = ((D2V) < K[s - 1]) ? ID[s - 1] : (((D2V) < K[s]) ? (JV) : ID[s]);\
        K[s]  = MED3((D2V), K[s - 1], K[s]);                                     \
    }                                                                            \
    ID[0] = ((D2V) < K[0]) ? (JV) : ID[0];                                       \
    K[0]  = __builtin_fminf((D2V), K[0]);                                        \
}

// ---------------- Phase 1: nearest-neighbor chain (k=1), writes outx ----------------
// r15-verified compute core + double-buffered LDS staging: frame t+1's global
// loads are issued before compute(t), ds_write to the opposite buffer, one
// barrier per iteration. Staged values and compute identical -> outx bitwise
// identical to the verified chain.
__global__ __launch_bounds__(256) void chain_k(const float* __restrict__ P,
                                               float* __restrict__ outx) {
    __shared__ float4 sF[2][NN];
    const int tid = threadIdx.x;
    const int bid = blockIdx.x;
    const int b = bid >> 7;
    const int qb = (bid & 127) << 3;
    const int ln = tid & 63;
    const int q = qb + ((tid >> 6) << 1) + (ln >> 5);
    const int sl = ln & 31;
    const float* bp = P + (size_t)b * NT * NN * 3;

    float cx = bp[q * 3 + 0], cy = bp[q * 3 + 1], cz = bp[q * 3 + 2];

    // prologue: stage frame 0 into buffer 0
    {
        const float4* f4 = (const float4*)bp;
        float4 A = f4[tid * 3 + 0], Bv = f4[tid * 3 + 1], C = f4[tid * 3 + 2];
        sF[0][tid * 4 + 0] = make_float4(A.x, A.y, A.z, sq3(A.x, A.y, A.z));
        sF[0][tid * 4 + 1] = make_float4(A.w, Bv.x, Bv.y, sq3(A.w, Bv.x, Bv.y));
        sF[0][tid * 4 + 2] = make_float4(Bv.z, Bv.w, C.x, sq3(Bv.z, Bv.w, C.x));
        sF[0][tid * 4 + 3] = make_float4(C.y, C.z, C.w, sq3(C.y, C.z, C.w));
    }
    __syncthreads();

    int buf = 0;
    for (int t = 0; t < NT; ++t) {
        // issue next frame's global loads BEFORE compute (latency hides under it)
        float4 A2, B2, C2;
        if (t < NT - 1) {
            const float4* g4 = (const float4*)(bp + (size_t)(t + 1) * NN * 3);
            A2 = g4[tid * 3 + 0]; B2 = g4[tid * 3 + 1]; C2 = g4[tid * 3 + 2];
        }

        // ---- compute on sF[buf] (identical to verified chain) ----
        float q2 = sq3(cx, cy, cz);
        float bd = F32_INF;
        u32 bj = 0u;
        #pragma unroll 8
        for (int i = 0; i < 32; ++i) {
            int j = (i << 5) | sl;          // ascending per lane -> stable in-lane
            float d2 = d2f(cx, cy, cz, q2, sF[buf][j]);
            bool c_ = d2 < bd;
            bd = c_ ? d2 : bd;
            bj = c_ ? (u32)j : bj;
        }
        // cross-lane exact argmin with lowest-index tie-break via packed key
        u64 key = ((u64)fmap(bd) << 32) | (u64)bj;
        #pragma unroll
        for (int off = 1; off < 32; off <<= 1) {
            u64 o = __shfl_xor(key, off);
            key = (o < key) ? o : key;
        }
        int bi = (int)((u32)key & 1023u);
        float4 w = sF[buf][bi];
        cx = w.x; cy = w.y; cz = w.z;
        if (sl == 0) {
            float* o = outx + ((size_t)(b * NT + t) * NN + q) * 3;
            o[0] = cx; o[1] = cy; o[2] = cz;
        }

        // ---- stage t+1 into the opposite buffer (no conflict with reads of buf) ----
        if (t < NT - 1) {
            sF[buf ^ 1][tid * 4 + 0] = make_float4(A2.x, A2.y, A2.z, sq3(A2.x, A2.y, A2.z));
            sF[buf ^ 1][tid * 4 + 1] = make_float4(A2.w, B2.x, B2.y, sq3(A2.w, B2.x, B2.y));
            sF[buf ^ 1][tid * 4 + 2] = make_float4(B2.z, B2.w, C2.x, sq3(B2.z, B2.w, C2.x));
            sF[buf ^ 1][tid * 4 + 3] = make_float4(C2.y, C2.z, C2.w, sq3(C2.y, C2.z, C2.w));
        }
        __syncthreads();  // publishes t+1 staging; all waves done reading sF[buf]
        buf ^= 1;
    }
}

// ---------------- Phase 2: exact LDS filter + PIPELINED bitmask replay --------------
// r18-HW-verified (best measured) — kept verbatim.
__global__ __launch_bounds__(256, 4) void topk_k(const float* __restrict__ P,
                                                 const float* __restrict__ outx,
                                                 float* __restrict__ out) {
    __shared__ float4 sC[NN];  // frame t   (x,y,z,|p|^2) 16KB
    __shared__ float4 sPv[NN]; // frame t-1 (x,y,z,0)     16KB
    const int tid = threadIdx.x;
    const int bid = blockIdx.x;
    const int b = bid >> 7;
    const int t = (bid >> 2) & 31;
    const int qc = bid & 3;
    const int q = (qc << 8) | tid;
    const float* bp = P + (size_t)b * NT * NN * 3;

    {
        const float4* f4 = (const float4*)(bp + (size_t)t * NN * 3);
        float4 A = f4[tid * 3 + 0], Bv = f4[tid * 3 + 1], C = f4[tid * 3 + 2];
        sC[tid * 4 + 0] = make_float4(A.x, A.y, A.z, sq3(A.x, A.y, A.z));
        sC[tid * 4 + 1] = make_float4(A.w, Bv.x, Bv.y, sq3(A.w, Bv.x, Bv.y));
        sC[tid * 4 + 2] = make_float4(Bv.z, Bv.w, C.x, sq3(Bv.z, Bv.w, C.x));
        sC[tid * 4 + 3] = make_float4(C.y, C.z, C.w, sq3(C.y, C.z, C.w));
        int tp = (t == 0) ? 0 : (t - 1);
        const float4* g4 = (const float4*)(bp + (size_t)tp * NN * 3);
        A = g4[tid * 3 + 0]; Bv = g4[tid * 3 + 1]; C = g4[tid * 3 + 2];
        sPv[tid * 4 + 0] = make_float4(A.x, A.y, A.z, 0.f);
        sPv[tid * 4 + 1] = make_float4(A.w, Bv.x, Bv.y, 0.f);
        sPv[tid * 4 + 2] = make_float4(Bv.z, Bv.w, C.x, 0.f);
        sPv[tid * 4 + 3] = make_float4(C.y, C.z, C.w, 0.f);
    }
    __syncthreads();

    // query point: x_cur(b,t,q)
    float cx, cy, cz;
    if (t == 0) {
        const float* qp = bp + (size_t)q * 3;
        cx = qp[0]; cy = qp[1]; cz = qp[2];
    } else {
        const float* qp = outx + ((size_t)(b * NT + (t - 1)) * NN + q) * 3;
        cx = qp[0]; cy = qp[1]; cz = qp[2];
    }
    // anchor = pts[b, t=0, q, k=0] = outx[b][0][q]
    const float* ap = outx + ((size_t)(b * NT) * NN + q) * 3;
    float ax = ap[0], ay = ap[1], az = ap[2];

    float q2 = sq3(cx, cy, cz);
    float K[KSEL];
    u32 ID[KSEL];
    #pragma unroll
    for (int i = 0; i < KSEL; i++) { K[i] = F32_INF; ID[i] = 0u; }

    // ---- chunk 0: direct exact fill, pipelined 1-ahead ----
    {
        float4 c_cur = sC[0];
        #pragma unroll 4
        for (int j = 0; j < 64; ++j) {
            float4 c_nxt = sC[(j < 63) ? (j + 1) : 63];  // prefetch before insert
            float d2 = d2f(cx, cy, cz, q2, c_cur);
            INSERT16(d2, (u32)j)
            c_cur = c_nxt;
        }
    }
    float thr = K[KSEL - 1];

    // ---- chunks 1..15: exact LDS filter + pipelined bitmask exact replay ----
    for (int ch = 1; ch < 16; ++ch) {
        u32 mlo = 0u, mhi = 0u;
        #pragma unroll
        for (int jj = 0; jj < 64; ++jj) {
            float d2 = d2f(cx, cy, cz, q2, sC[(ch << 6) | jj]);
            bool h = d2 < thr;
            if (jj < 32) mlo |= h ? (1u << jj) : 0u;
            else         mhi |= h ? (1u << (jj - 32)) : 0u;
        }
        u64 msk = ((u64)mhi << 32) | (u64)mlo;
        int cm = __builtin_popcountll(msk);
        #pragma unroll
        for (int off = 1; off < 64; off <<= 1) {
            int o = __shfl_xor(cm, off);
            cm = (o > cm) ? o : cm;
        }
        cm = __builtin_amdgcn_readfirstlane(cm);

        // peel: extract first survivor + issue its load
        bool act_c = msk != 0ull;
        u64 mm0 = act_c ? msk : 1ull;
        u32 j_cur = ((u32)ch << 6) | (u32)__builtin_ctzll(mm0);
        msk &= (msk - 1ull);
        float4 c_cur = sC[j_cur];

        for (int i = 0; i < cm; ++i) {
            // extract NEXT survivor and issue its load before the current insert
            bool act_n = msk != 0ull;
            u64 mmn = act_n ? msk : 1ull;
            u32 j_nxt = ((u32)ch << 6) | (u32)__builtin_ctzll(mmn);
            msk &= (msk - 1ull);
            float4 c_nxt = sC[j_nxt];

            float d2 = d2f(cx, cy, cz, q2, c_cur);
            float d2v = act_c ? d2 : F32_INF;  // neutralize exhausted lanes
            INSERT16(d2v, j_cur)

            j_cur = j_nxt; c_cur = c_nxt; act_c = act_n;
        }
        thr = K[KSEL - 1];
    }

    size_t g = (size_t)(b * NT + t) * NN + q;

    // idxs (x2) and dist
    #pragma unroll
    for (int kk = 0; kk < KSEL; kk += 4) {
        float4 fi = make_float4((float)ID[kk + 0], (float)ID[kk + 1],
                                (float)ID[kk + 2], (float)ID[kk + 3]);
        float4 fd = make_float4(K[kk + 0], K[kk + 1], K[kk + 2], K[kk + 3]);
        *(float4*)(out + O_IDX0 + g * 16 + kk) = fi;
        *(float4*)(out + O_IDX1 + g * 16 + kk) = fi;
        *(float4*)(out + O_DIST + g * 16 + kk) = fd;
    }

    // pts, normalized, patchlet_feats
    #pragma unroll
    for (int kk = 0; kk < KSEL; kk += 4) {
        u32 i0 = ID[kk + 0], i1 = ID[kk + 1], i2 = ID[kk + 2], i3 = ID[kk + 3];
        float4 p0 = sC[i0], p1 = sC[i1], p2v = sC[i2], p3 = sC[i3];
        float4 f0 = sPv[i0], f1 = sPv[i1], f2v = sPv[i2], f3 = sPv[i3];
        float n0x = p0.x - ax, n0y = p0.y - ay, n0z = p0.z - az;
        float n1x = p1.x - ax, n1y = p1.y - ay, n1z = p1.z - az;
        float n2x = p2v.x - ax, n2y = p2v.y - ay, n2z = p2v.z - az;
        float n3x = p3.x - ax, n3y = p3.y - ay, n3z = p3.z - az;

        float* pp = out + O_PTS + g * 48 + kk * 3;
        ((float4*)pp)[0] = make_float4(p0.x, p0.y, p0.z, p1.x);
        ((float4*)pp)[1] = make_float4(p1.y, p1.z, p2v.x, p2v.y);
        ((float4*)pp)[2] = make_float4(p2v.z, p3.x, p3.y, p3.z);

        float* np = out + O_NORM + g * 48 + kk * 3;
        ((float4*)np)[0] = make_float4(n0x, n0y, n0z, n1x);
        ((float4*)np)[1] = make_float4(n1y, n1z, n2x, n2y);
        ((float4*)np)[2] = make_float4(n2z, n3x, n3y, n3z);

        float* fp = out + O_PF + g * 96 + kk * 6;
        ((float4*)fp)[0] = make_float4(f0.x, f0.y, f0.z, n0x);
        ((float4*)fp)[1] = make_float4(n0y, n0z, f1.x, f1.y);
        ((float4*)fp)[2] = make_float4(f1.z, n1x, n1y, n1z);
        ((float4*)fp)[3] = make_float4(f2v.x, f2v.y, f2v.z, n2x);
        ((float4*)fp)[4] = make_float4(n2y, n2z, f3.x, f3.y);
        ((float4*)fp)[5] = make_float4(f3.z, n3x, n3y, n3z);
    }
}

extern "C" void kernel_launch(void* const* d_in, const int* in_sizes, int n_in,
                              void* d_out, int out_size, void* d_ws, size_t ws_size,
                              hipStream_t stream) {
    const float* P = (const float*)d_in[0];
    float* out = (float*)d_out;
    float* outx = out + O_OUTX;
    chain_k<<<dim3(1024), dim3(256), 0, stream>>>(P, outx);
    topk_k<<<dim3(1024), dim3(256), 0, stream>>>(P, outx, out);
}